// Round 1
// baseline (146.978 us; speedup 1.0000x reference)
//
#include <hip/hip_runtime.h>
#include <hip/hip_bf16.h>
#include <stdint.h>

#define NB    65536
#define FEATN 261
#define HIDN  128
#define NSTEP 17           // 17 MFMA k-steps of 16
#define SROW  296          // LDS A row stride in halfwords (rows 16B-aligned)

#define ROWSF 64           // rows per fused block
#define NTHRF 256

typedef __attribute__((ext_vector_type(8)))  short bf16x8;   // 8 bf16 = 4 VGPRs
typedef __attribute__((ext_vector_type(16))) float f32x16;   // 32x32 accum
typedef float f32x4u __attribute__((ext_vector_type(4), aligned(4)));  // dword-aligned float4

#define MFMA32(A, B, C) __builtin_amdgcn_mfma_f32_32x32x16_bf16(A, B, C, 0, 0, 0)

__device__ __forceinline__ uint16_t f2b(float v) {
    __hip_bfloat16 b = __float2bfloat16(v);
    return *reinterpret_cast<uint16_t*>(&b);
}

// ---------- prep kernel: pack Wc1 into MFMA B-fragment order ----------
// piece p = s*4+nt; lane l: n = nt*32+(l&31), k = 16s + 8*(l>>5) + j,
// zero-padded past k=260.
__global__ void prep_kernel(const float* __restrict__ Wc1,
                            uint16_t* __restrict__ wsB)
{
    int t = blockIdx.x * 256 + threadIdx.x;
    if (t < NSTEP * 4 * 64) {
        int p = t >> 6, l = t & 63;
        int s = p >> 2, nt = p & 3;
        int n = nt * 32 + (l & 31);
        int kb = 16 * s + 8 * (l >> 5);
        uint16_t hw[8];
        #pragma unroll
        for (int j = 0; j < 8; ++j) {
            int k = kb + j;
            float v = (k < FEATN) ? Wc1[(size_t)k * HIDN + n] : 0.f;
            hw[j] = f2b(v);
        }
        *reinterpret_cast<uint4*>(wsB + (size_t)p * 512 + l * 8) =
            *reinterpret_cast<uint4*>(hw);
    }
}

// ---------- fused kernel: 64 rows/block, 256 threads ----------
// stage x->LDS (bf16) ; tree on global f32 (L1/L2-hot) ; barrier ; GEMM.
// x is read from HBM exactly once.
__global__ __launch_bounds__(NTHRF, 4) void fused_kernel(
    const float* __restrict__ x,
    const float* __restrict__ w0, const float* __restrict__ b0,
    const float* __restrict__ w1, const float* __restrict__ b1,
    const float* __restrict__ w2, const float* __restrict__ b2,
    const float* __restrict__ leaf,
    const uint16_t* __restrict__ wsB,
    const float* __restrict__ bc1, const float* __restrict__ Wc2,
    const float* __restrict__ bc2,
    float* __restrict__ out_p, float* __restrict__ out_v)
{
    __shared__ uint16_t Axs[ROWSF * SROW];     // 37,888 B
    __shared__ float bc1s[HIDN];
    __shared__ float wc2s[HIDN];
    __shared__ float vpart[ROWSF * 2];

    const int tid = threadIdx.x;
    const int rowBase = blockIdx.x * ROWSF;

    if (tid < HIDN) { bc1s[tid] = bc1[tid]; wc2s[tid] = Wc2[tid]; }
    if (tid < ROWSF) {                          // zero k = 261..295 pad
        uint16_t* rp = Axs + tid * SROW;
        rp[261] = 0;
        *reinterpret_cast<uint32_t*>(rp + 262) = 0u;
        uint4 z; z.x = z.y = z.z = z.w = 0u;
        *reinterpret_cast<uint4*>(rp + 264) = z;
        *reinterpret_cast<uint4*>(rp + 272) = z;
        *reinterpret_cast<uint4*>(rp + 280) = z;
        *reinterpret_cast<uint4*>(rp + 288) = z;
    }

    // ---- stage: (row,seg); seg = 4 floats -> one ds_write_b64 of 4 bf16 ----
    for (int idx = tid; idx < ROWSF * 66; idx += NTHRF) {
        int row = idx / 66;
        int seg = idx - row * 66;
        const float* src = x + (size_t)(rowBase + row) * FEATN + 4 * seg;
        uint16_t* dst = Axs + row * SROW + 4 * seg;
        if (seg < 65) {
            f32x4u v = *reinterpret_cast<const f32x4u*>(src);
            uint32_t p0 = (uint32_t)f2b(v[0]) | ((uint32_t)f2b(v[1]) << 16);
            uint32_t p1 = (uint32_t)f2b(v[2]) | ((uint32_t)f2b(v[3]) << 16);
            uint2 pk; pk.x = p0; pk.y = p1;
            *reinterpret_cast<uint2*>(dst) = pk;   // ds_write_b64
        } else {
            dst[0] = f2b(src[0]);                  // k = 260 only
        }
    }

    // ---- tree: 16 lanes/row, 4 rows per 16-lane group, x reads are
    //      L1/L2-hot (just staged). Runs before the barrier so the
    //      ds_write drain hides under it. ----
    {
        const int s = tid & 15;
        const int g = tid >> 4;

        // weights hoisted once per thread (amortized over 4 rows)
        f32x4u w0q[4];
        #pragma unroll
        for (int j = 0; j < 4; ++j)
            w0q[j] = *reinterpret_cast<const f32x4u*>(w0 + 4 * s + 64 * j);
        const float w0t = (s < 5) ? w0[256 + s] : 0.f;

        f32x4u w1aq[2], w1bq[2];
        #pragma unroll
        for (int j = 0; j < 2; ++j) {
            w1aq[j] = *reinterpret_cast<const f32x4u*>(w1 + 5 + 8 * s + 4 * j);
            w1bq[j] = *reinterpret_cast<const f32x4u*>(w1 + 133 + 5 + 8 * s + 4 * j);
        }
        const float w1a5 = (s < 5) ? w1[s]       : 0.f;
        const float w1b5 = (s < 5) ? w1[133 + s] : 0.f;

        f32x4u w2q0 = *reinterpret_cast<const f32x4u*>(w2 +  0 * 69 + 5 + 4 * s);
        f32x4u w2q1 = *reinterpret_cast<const f32x4u*>(w2 +  1 * 69 + 5 + 4 * s);
        f32x4u w2q2 = *reinterpret_cast<const f32x4u*>(w2 +  2 * 69 + 5 + 4 * s);
        f32x4u w2q3 = *reinterpret_cast<const f32x4u*>(w2 +  3 * 69 + 5 + 4 * s);
        const float w25_0 = (s < 5) ? w2[0 * 69 + s] : 0.f;
        const float w25_1 = (s < 5) ? w2[1 * 69 + s] : 0.f;
        const float w25_2 = (s < 5) ? w2[2 * 69 + s] : 0.f;
        const float w25_3 = (s < 5) ? w2[3 * 69 + s] : 0.f;

        #pragma unroll 1
        for (int r4 = 0; r4 < 4; ++r4) {
            const int row = rowBase + r4 * 16 + g;
            const float* xr = x + (size_t)row * FEATN;

            f32x4u xq[4];
            #pragma unroll
            for (int j = 0; j < 4; ++j)
                xq[j] = *reinterpret_cast<const f32x4u*>(xr + 4 * s + 64 * j);
            const float xt  = (s < 5) ? xr[256 + s] : 0.f;
            const float xs5 = (s < 5) ? xr[s]       : 0.f;

            // level 0
            float part = xt * w0t;
            #pragma unroll
            for (int j = 0; j < 4; ++j)
                #pragma unroll
                for (int c = 0; c < 4; ++c)
                    part += xq[j][c] * w0q[j][c];
            part += __shfl_xor(part, 1);
            part += __shfl_xor(part, 2);
            part += __shfl_xor(part, 4);
            part += __shfl_xor(part, 8);
            float gate = part + b0[0];
            int node = (gate >= 0.f) ? 1 : 0;
            float cum = 1.f / (1.f + __expf(-gate));

            // level 1
            {
                const float* base = xr + 5 + 128 * node + 8 * s;
                f32x4u xw0 = *reinterpret_cast<const f32x4u*>(base);
                f32x4u xw1 = *reinterpret_cast<const f32x4u*>(base + 4);
                part = xs5 * (node ? w1b5 : w1a5);
                #pragma unroll
                for (int c = 0; c < 4; ++c) {
                    part += xw0[c] * (node ? w1bq[0][c] : w1aq[0][c]);
                    part += xw1[c] * (node ? w1bq[1][c] : w1aq[1][c]);
                }
                part += __shfl_xor(part, 1);
                part += __shfl_xor(part, 2);
                part += __shfl_xor(part, 4);
                part += __shfl_xor(part, 8);
                gate = part + b1[node];
                cum *= 1.f / (1.f + __expf(-gate));
                node = node * 2 + ((gate >= 0.f) ? 1 : 0);
            }
            // level 2
            {
                f32x4u xv2 = *reinterpret_cast<const f32x4u*>(xr + 5 + 64 * node + 4 * s);
                f32x4u t0 = (node & 1) ? w2q1 : w2q0;
                f32x4u t1 = (node & 1) ? w2q3 : w2q2;
                f32x4u wsel = (node & 2) ? t1 : t0;
                float w5a = (node & 1) ? w25_1 : w25_0;
                float w5b = (node & 1) ? w25_3 : w25_2;
                float w5sel = (node & 2) ? w5b : w5a;
                part = xs5 * w5sel;
                #pragma unroll
                for (int c = 0; c < 4; ++c) part += xv2[c] * wsel[c];
                part += __shfl_xor(part, 1);
                part += __shfl_xor(part, 2);
                part += __shfl_xor(part, 4);
                part += __shfl_xor(part, 8);
                gate = part + b2[node];
                cum *= 1.f / (1.f + __expf(-gate));
                node = node * 2 + ((gate >= 0.f) ? 1 : 0);
            }
            if (s < 8)
                out_p[(size_t)row * 8 + s] = cum * leaf[node * 8 + s];
        }
    }

    __syncthreads();

    // ---- GEMM: 4 waves; wave w: m-tile mt=w>>1 (0..1), n-half nh=w&1.
    //      A/B fragments streamed in-loop (keeps VGPR <= 128 for 4 blk/CU). ----
    const int lane = tid & 63;
    const int w    = tid >> 6;
    const int mt   = w >> 1;
    const int nh   = w & 1;

    const uint16_t* arow = Axs + (mt * 32 + (lane & 31)) * SROW + (lane >> 5) * 8;
    const uint16_t* bgl  = wsB + (size_t)(2 * nh) * 512 + lane * 8;

    f32x16 acc0 = {}, acc1 = {};
    #pragma unroll
    for (int ss = 0; ss < NSTEP; ++ss) {
        bf16x8 af  = *reinterpret_cast<const bf16x8*>(arow + ss * 16);
        bf16x8 bf0 = *reinterpret_cast<const bf16x8*>(bgl + (size_t)(ss * 4)     * 512);
        bf16x8 bf1 = *reinterpret_cast<const bf16x8*>(bgl + (size_t)(ss * 4 + 1) * 512);
        acc0 = MFMA32(af, bf0, acc0);
        acc1 = MFMA32(af, bf1, acc1);
    }

    // ---- epilogue: bias+relu+Wc2 dot, cross-lane reduce, v write ----
    {
        const int c = lane & 31;
        const int q = lane >> 5;
        const int n0 = 2 * nh * 32 + c;
        const int n1 = n0 + 32;
        const float bb0 = bc1s[n0], ww0 = wc2s[n0];
        const float bb1 = bc1s[n1], ww1 = wc2s[n1];

        float pv[16];
        #pragma unroll
        for (int reg = 0; reg < 16; ++reg) {
            float h0 = acc0[reg] + bb0; h0 = h0 > 0.f ? h0 : 0.f;
            float h1 = acc1[reg] + bb1; h1 = h1 > 0.f ? h1 : 0.f;
            float t = h0 * ww0 + h1 * ww1;
            t += __shfl_xor(t, 1);
            t += __shfl_xor(t, 2);
            t += __shfl_xor(t, 4);
            t += __shfl_xor(t, 8);
            t += __shfl_xor(t, 16);
            pv[reg] = t;
        }
        #pragma unroll
        for (int reg = 0; reg < 16; ++reg) {
            if (c == reg) {
                int row_local = (reg & 3) + 8 * (reg >> 2) + 4 * q;
                vpart[(mt * 32 + row_local) * 2 + nh] = pv[reg];
            }
        }
    }
    __syncthreads();
    if (tid < ROWSF)
        out_v[rowBase + tid] = vpart[tid * 2] + vpart[tid * 2 + 1] + bc2[0];
}

extern "C" void kernel_launch(void* const* d_in, const int* in_sizes, int n_in,
                              void* d_out, int out_size, void* d_ws, size_t ws_size,
                              hipStream_t stream) {
    const float* x    = (const float*)d_in[0];
    const float* w0   = (const float*)d_in[1];
    const float* b0   = (const float*)d_in[2];
    const float* w1   = (const float*)d_in[3];
    const float* b1   = (const float*)d_in[4];
    const float* w2   = (const float*)d_in[5];
    const float* b2   = (const float*)d_in[6];
    const float* leaf = (const float*)d_in[7];
    const float* Wc1  = (const float*)d_in[8];
    const float* bc1  = (const float*)d_in[9];
    const float* Wc2  = (const float*)d_in[10];
    const float* bc2  = (const float*)d_in[11];

    uint16_t* wsB = (uint16_t*)d_ws;     // 17*4*1024 = 69632 B, frag order

    float* out_p = (float*)d_out;
    float* out_v = out_p + (size_t)NB * 8;

    prep_kernel<<<17, 256, 0, stream>>>(Wc1, wsB);
    fused_kernel<<<NB / ROWSF, NTHRF, 0, stream>>>(
        x, w0, b0, w1, b1, w2, b2, leaf, wsB, bc1, Wc2, bc2, out_p, out_v);
}

// Round 2
// 127.580 us; speedup vs baseline: 1.1521x; 1.1521x over previous
//
#include <hip/hip_runtime.h>
#include <hip/hip_bf16.h>
#include <stdint.h>

#define NB    65536
#define FEATN 261
#define HIDN  128
#define NSTEP 17           // 17 MFMA k-steps of 16
#define SROW  296          // LDS A row stride in halfwords (rows 16B-aligned)

#define ROWSF 64           // rows per fused block
#define NTHRF 256

typedef __attribute__((ext_vector_type(8)))  short bf16x8;   // 8 bf16 = 4 VGPRs
typedef __attribute__((ext_vector_type(16))) float f32x16;   // 32x32 accum
typedef float f32x4u __attribute__((ext_vector_type(4), aligned(4)));  // dword-aligned float4

#define MFMA32(A, B, C) __builtin_amdgcn_mfma_f32_32x32x16_bf16(A, B, C, 0, 0, 0)

__device__ __forceinline__ uint16_t f2b(float v) {
    __hip_bfloat16 b = __float2bfloat16(v);
    return *reinterpret_cast<uint16_t*>(&b);
}

__device__ __forceinline__ float sigmoidf(float g) {
    return 1.f / (1.f + __expf(-g));
}

#define RED16(v) do { v += __shfl_xor(v, 1); v += __shfl_xor(v, 2); \
                      v += __shfl_xor(v, 4); v += __shfl_xor(v, 8); } while (0)

// ---------- prep kernel: pack Wc1 into MFMA B-fragment order ----------
__global__ void prep_kernel(const float* __restrict__ Wc1,
                            uint16_t* __restrict__ wsB)
{
    int t = blockIdx.x * 256 + threadIdx.x;
    if (t < NSTEP * 4 * 64) {
        int p = t >> 6, l = t & 63;
        int s = p >> 2, nt = p & 3;
        int n = nt * 32 + (l & 31);
        int kb = 16 * s + 8 * (l >> 5);
        uint16_t hw[8];
        #pragma unroll
        for (int j = 0; j < 8; ++j) {
            int k = kb + j;
            float v = (k < FEATN) ? Wc1[(size_t)k * HIDN + n] : 0.f;
            hw[j] = f2b(v);
        }
        *reinterpret_cast<uint4*>(wsB + (size_t)p * 512 + l * 8) =
            *reinterpret_cast<uint4*>(hw);
    }
}

// ---------- fused kernel: 64 rows/block, 256 threads ----------
// One load of x per row feeds BOTH the LDS staging (bf16, for MFMA) and the
// tree (all 7 candidate gates computed from the same registers — zero
// node-dependent loads).
__global__ __launch_bounds__(NTHRF, 4) void fused_kernel(
    const float* __restrict__ x,
    const float* __restrict__ w0, const float* __restrict__ b0,
    const float* __restrict__ w1, const float* __restrict__ b1,
    const float* __restrict__ w2, const float* __restrict__ b2,
    const float* __restrict__ leaf,
    const uint16_t* __restrict__ wsB,
    const float* __restrict__ bc1, const float* __restrict__ Wc2,
    const float* __restrict__ bc2,
    float* __restrict__ out_p, float* __restrict__ out_v)
{
    __shared__ uint16_t Axs[ROWSF * SROW];     // 37,888 B
    __shared__ float bc1s[HIDN];
    __shared__ float wc2s[HIDN];
    __shared__ float vpart[ROWSF * 2];

    const int tid = threadIdx.x;
    const int rowBase = blockIdx.x * ROWSF;

    if (tid < HIDN) { bc1s[tid] = bc1[tid]; wc2s[tid] = Wc2[tid]; }
    if (tid < ROWSF) {                          // zero k = 261..295 pad
        uint16_t* rp = Axs + tid * SROW;
        rp[261] = 0;
        *reinterpret_cast<uint32_t*>(rp + 262) = 0u;
        uint4 z; z.x = z.y = z.z = z.w = 0u;
        *reinterpret_cast<uint4*>(rp + 264) = z;
        *reinterpret_cast<uint4*>(rp + 272) = z;
        *reinterpret_cast<uint4*>(rp + 280) = z;
        *reinterpret_cast<uint4*>(rp + 288) = z;
    }

    const int s = tid & 15;     // lane-in-group: owns elements e = 64j+4s+c
    const int g = tid >> 4;     // group 0..15: rows r4*16+g

    // ---- hoisted per-lane weight tables (once per thread, 4 rows reuse) ----
    // element e routing: L1 node = (e>=133), flat w1 idx = e + 5*(e>=133)
    //                    L2 node n2 = (e<5)?0:((e-5)>>6), flat idx = e + 5*n2
    f32x4u w0q[4];
    #pragma unroll
    for (int j = 0; j < 4; ++j)
        w0q[j] = *reinterpret_cast<const f32x4u*>(w0 + 64 * j + 4 * s);
    const float w0t = (s < 5) ? w0[256 + s] : 0.f;

    float w1v[4][4], w2v[4][4];
    #pragma unroll
    for (int j = 0; j < 4; ++j)
        #pragma unroll
        for (int c = 0; c < 4; ++c) {
            int e = 64 * j + 4 * s + c;
            w1v[j][c] = w1[(e < 133) ? e : e + 5];
            int n2 = (e < 5) ? 0 : ((e - 5) >> 6);
            w2v[j][c] = w2[e + 5 * n2];
        }
    const float w1t = (s < 5) ? w1[261 + s] : 0.f;   // tail e=256+s -> L1 node1
    const float w2t = (s < 5) ? w2[271 + s] : 0.f;   // tail -> L2 node3

    // x5 cross-terms: e<5 contributes to ALL nodes; element path covers node0.
    const float xw1b  = (s < 5) ? w1[133 + s] : 0.f;
    const float xw2_1 = (s < 5) ? w2[ 69 + s] : 0.f;
    const float xw2_2 = (s < 5) ? w2[138 + s] : 0.f;
    const float xw2_3 = (s < 5) ? w2[207 + s] : 0.f;

    const float b0s  = b0[0];
    const float b1s0 = b1[0], b1s1 = b1[1];
    const float b2s0 = b2[0], b2s1 = b2[1], b2s2 = b2[2], b2s3 = b2[3];

    #pragma unroll 1
    for (int r4 = 0; r4 < 4; ++r4) {
        const int rl  = r4 * 16 + g;
        const int row = rowBase + rl;
        const float* xr = x + (size_t)row * FEATN;

        // ---- the ONLY x loads for this row (no dependent loads below) ----
        f32x4u xq[4];
        #pragma unroll
        for (int j = 0; j < 4; ++j)
            xq[j] = *reinterpret_cast<const f32x4u*>(xr + 64 * j + 4 * s);
        const float xt  = (s < 5) ? xr[256 + s] : 0.f;
        const float xs5 = (s < 5) ? xr[s]       : 0.f;

        // ---- stage to LDS (bf16) from the same registers ----
        {
            uint16_t* rp = Axs + rl * SROW;
            #pragma unroll
            for (int j = 0; j < 4; ++j) {
                uint32_t p0w = (uint32_t)f2b(xq[j][0]) | ((uint32_t)f2b(xq[j][1]) << 16);
                uint32_t p1w = (uint32_t)f2b(xq[j][2]) | ((uint32_t)f2b(xq[j][3]) << 16);
                uint2 pk; pk.x = p0w; pk.y = p1w;
                *reinterpret_cast<uint2*>(rp + 64 * j + 4 * s) = pk;  // ds_write_b64
            }
            if (s < 5) rp[256 + s] = f2b(xt);
        }

        // ---- 7 candidate-gate partials in one pass over registers ----
        float p0 = 0.f, p1a = 0.f, p1b = 0.f;
        float p2_0 = 0.f, p2_1 = 0.f, p2_2 = 0.f, p2_3 = 0.f;
        #pragma unroll
        for (int j = 0; j < 4; ++j)
            #pragma unroll
            for (int c = 0; c < 4; ++c) {
                const float xv = xq[j][c];
                const bool lo = (4 * s + c) < 5;   // the only runtime seam
                p0 += xv * w0q[j][c];
                const float t1 = xv * w1v[j][c];
                const float t2 = xv * w2v[j][c];
                if (j == 0) {
                    p1a += t1;
                    p2_0 += t2;
                } else if (j == 1) {
                    p1a += t1;
                    p2_0 += lo ? t2 : 0.f;  p2_1 += lo ? 0.f : t2;
                } else if (j == 2) {
                    p1a += lo ? t1 : 0.f;   p1b += lo ? 0.f : t1;
                    p2_1 += lo ? t2 : 0.f;  p2_2 += lo ? 0.f : t2;
                } else {
                    p1b += t1;
                    p2_2 += lo ? t2 : 0.f;  p2_3 += lo ? 0.f : t2;
                }
            }
        // tails (e = 256+s) and x5 cross-terms
        p0   += xt * w0t;
        p1b  += xt * w1t;
        p2_3 += xt * w2t;
        p1b  += xs5 * xw1b;
        p2_1 += xs5 * xw2_1;
        p2_2 += xs5 * xw2_2;
        p2_3 += xs5 * xw2_3;

        // ---- select-then-reduce chain (no memory ops) ----
        RED16(p0);
        const float gate0 = p0 + b0s;
        int nn = (gate0 >= 0.f) ? 1 : 0;
        float cum = sigmoidf(gate0);

        float p1 = nn ? p1b : p1a;           // nn group-uniform after reduce
        RED16(p1);
        const float gate1 = p1 + (nn ? b1s1 : b1s0);
        nn = nn * 2 + ((gate1 >= 0.f) ? 1 : 0);
        cum *= sigmoidf(gate1);

        float p2 = (nn & 2) ? ((nn & 1) ? p2_3 : p2_2)
                            : ((nn & 1) ? p2_1 : p2_0);
        RED16(p2);
        const float gate2 = p2 + ((nn & 2) ? ((nn & 1) ? b2s3 : b2s2)
                                           : ((nn & 1) ? b2s1 : b2s0));
        nn = nn * 2 + ((gate2 >= 0.f) ? 1 : 0);
        cum *= sigmoidf(gate2);

        if (s < 8)
            out_p[(size_t)row * 8 + s] = cum * leaf[nn * 8 + s];
    }

    __syncthreads();

    // ---- GEMM: 4 waves; wave w: m-tile mt=w>>1 (0..1), n-half nh=w&1 ----
    const int lane = tid & 63;
    const int w    = tid >> 6;
    const int mt   = w >> 1;
    const int nh   = w & 1;

    const uint16_t* arow = Axs + (mt * 32 + (lane & 31)) * SROW + (lane >> 5) * 8;
    const uint16_t* bgl  = wsB + (size_t)(2 * nh) * 512 + lane * 8;

    f32x16 acc0 = {}, acc1 = {};
    #pragma unroll
    for (int ss = 0; ss < NSTEP; ++ss) {
        bf16x8 af  = *reinterpret_cast<const bf16x8*>(arow + ss * 16);
        bf16x8 bf0 = *reinterpret_cast<const bf16x8*>(bgl + (size_t)(ss * 4)     * 512);
        bf16x8 bf1 = *reinterpret_cast<const bf16x8*>(bgl + (size_t)(ss * 4 + 1) * 512);
        acc0 = MFMA32(af, bf0, acc0);
        acc1 = MFMA32(af, bf1, acc1);
    }

    // ---- epilogue: bias+relu+Wc2 dot, cross-lane reduce, v write ----
    {
        const int c = lane & 31;
        const int q = lane >> 5;
        const int n0 = 2 * nh * 32 + c;
        const int n1 = n0 + 32;
        const float bb0 = bc1s[n0], ww0 = wc2s[n0];
        const float bb1 = bc1s[n1], ww1 = wc2s[n1];

        float pv[16];
        #pragma unroll
        for (int reg = 0; reg < 16; ++reg) {
            float h0 = acc0[reg] + bb0; h0 = h0 > 0.f ? h0 : 0.f;
            float h1 = acc1[reg] + bb1; h1 = h1 > 0.f ? h1 : 0.f;
            float t = h0 * ww0 + h1 * ww1;
            t += __shfl_xor(t, 1);
            t += __shfl_xor(t, 2);
            t += __shfl_xor(t, 4);
            t += __shfl_xor(t, 8);
            t += __shfl_xor(t, 16);
            pv[reg] = t;
        }
        #pragma unroll
        for (int reg = 0; reg < 16; ++reg) {
            if (c == reg) {
                int row_local = (reg & 3) + 8 * (reg >> 2) + 4 * q;
                vpart[(mt * 32 + row_local) * 2 + nh] = pv[reg];
            }
        }
    }
    __syncthreads();
    if (tid < ROWSF)
        out_v[rowBase + tid] = vpart[tid * 2] + vpart[tid * 2 + 1] + bc2[0];
}

extern "C" void kernel_launch(void* const* d_in, const int* in_sizes, int n_in,
                              void* d_out, int out_size, void* d_ws, size_t ws_size,
                              hipStream_t stream) {
    const float* x    = (const float*)d_in[0];
    const float* w0   = (const float*)d_in[1];
    const float* b0   = (const float*)d_in[2];
    const float* w1   = (const float*)d_in[3];
    const float* b1   = (const float*)d_in[4];
    const float* w2   = (const float*)d_in[5];
    const float* b2   = (const float*)d_in[6];
    const float* leaf = (const float*)d_in[7];
    const float* Wc1  = (const float*)d_in[8];
    const float* bc1  = (const float*)d_in[9];
    const float* Wc2  = (const float*)d_in[10];
    const float* bc2  = (const float*)d_in[11];

    uint16_t* wsB = (uint16_t*)d_ws;     // 17*4*1024 = 69632 B, frag order

    float* out_p = (float*)d_out;
    float* out_v = out_p + (size_t)NB * 8;

    prep_kernel<<<17, 256, 0, stream>>>(Wc1, wsB);
    fused_kernel<<<NB / ROWSF, NTHRF, 0, stream>>>(
        x, w0, b0, w1, b1, w2, b2, leaf, wsB, bc1, Wc2, bc2, out_p, out_v);
}